// Round 15
// baseline (175.445 us; speedup 1.0000x reference)
//
#include <hip/hip_runtime.h>

#define NSLOPE  0.2f
#define LEXP(v) __expf((v) >= 0.f ? (v) : NSLOPE * (v))

typedef __attribute__((ext_vector_type(8))) short bf16x8;
typedef __attribute__((ext_vector_type(4))) float f32x4;

__device__ __forceinline__ unsigned bf16_rne(float f) {
    unsigned x = __float_as_uint(f);
    return (x + 0x7fffu + ((x >> 16) & 1u)) >> 16;
}
__device__ __forceinline__ float bf_lo(unsigned u) { return __uint_as_float(u << 16); }
__device__ __forceinline__ float bf_hi(unsigned u) { return __uint_as_float(u & 0xffff0000u); }

// ---- Kernel 1 (fused): blocks [0,512): h2 = bf16(x@W^T) via MFMA + att dots
// via 4 extra MFMAs against watt = att@W. Blocks [512,512+NBLKB): partB2
// (count + reserve + scatter into padded bucket regions). gcur holds RELATIVE
// counts (memset to 0 before launch) so there is no ordering dependency.
__global__ __launch_bounds__(256) void k_gemm_partB(
    const float* __restrict__ x, const float* __restrict__ Wg,
    const float* __restrict__ att_src, const float* __restrict__ att_dst,
    unsigned* __restrict__ h2, float* __restrict__ a_src, float* __restrict__ a_dst,
    int N, const int* __restrict__ ei, int* __restrict__ gcur,
    unsigned* __restrict__ stage, int E, int nbkt, int cap, int chunk)
{
    __shared__ unsigned short Wl[128 * 136];   // bf16 W (69.6KB as bytes)
    __shared__ unsigned short wattH[8][128];   // bf16 watt (2KB)

    const int t = threadIdx.x;

    if (blockIdx.x >= 512) {                   // ---- partB2 role ----
        const int blk = blockIdx.x - 512;
        int* dstc  = (int*)Wl;                 // 6272 ints   (25088 B)
        int* lcnt  = dstc + 6272;              // 1024 ints
        int* lbase = lcnt + 1024;              // 1024 ints   (33280 B total)
        for (int i = t; i < nbkt; i += 256) lcnt[i] = 0;
        __syncthreads();
        const int lo = blk * chunk, hi = min(lo + chunk, E);
        for (int e = lo + t; e < hi; e += 256) {
            int d = ei[E + e];
            dstc[e - lo] = d;
            atomicAdd(&lcnt[d >> 7], 1);
        }
        __syncthreads();
        for (int i = t; i < nbkt; i += 256) {
            int c = lcnt[i];
            lbase[i] = (c > 0) ? (i * cap + atomicAdd(&gcur[i], c)) : 0;
        }
        __syncthreads();
        for (int e = lo + t; e < hi; e += 256) {
            int s = ei[e];
            int d = dstc[e - lo];
            int pos = atomicAdd(&lbase[d >> 7], 1);
            stage[pos] = (unsigned)s | ((unsigned)(d & 127) << 25);
        }
        return;
    }

    // ---- GEMM role ----
    for (int i = t; i < 128 * 32; i += 256) {
        int r = i >> 5, c4 = (i & 31) * 4;
        float4 w = *(const float4*)(Wg + r * 128 + c4);
        unsigned* wp = (unsigned*)((char*)Wl + r * 272 + c4 * 2);
        wp[0] = bf16_rne(w.x) | (bf16_rne(w.y) << 16);
        wp[1] = bf16_rne(w.z) | (bf16_rne(w.w) << 16);
    }
    // watt[j][f]: j<4 -> src head j; j>=4 -> dst head j-4
    for (int idx = t; idx < 1024; idx += 256) {
        int j = idx >> 7, f = idx & 127;
        const float* av = (j < 4) ? (att_src + j * 32) : (att_dst + (j - 4) * 32);
        int hh = (j & 3) * 32;
        float s = 0.f;
        #pragma unroll 8
        for (int k = 0; k < 32; ++k)
            s += av[k] * Wg[(size_t)(hh + k) * 128 + f];
        wattH[j][f] = (unsigned short)bf16_rne(s);
    }
    __syncthreads();

    const int wave = t >> 6, l = t & 63;
    const int col = l & 15, kg = l >> 4;

    union { bf16x8 v; unsigned short s[8]; } batt[4];
    #pragma unroll
    for (int s4 = 0; s4 < 4; ++s4) {
        #pragma unroll
        for (int jj = 0; jj < 8; ++jj)
            batt[s4].s[jj] = (col < 8) ? wattH[col][s4 * 32 + kg * 8 + jj]
                                       : (unsigned short)0;
    }

    const int nwaves = 512 * 4;
    const int wid = blockIdx.x * 4 + wave;

    for (int mb = wid * 16; mb < N; mb += nwaves * 16) {
        union { bf16x8 v; unsigned u[4]; } af[4];
        int row = mb + col; if (row >= N) row = N - 1;
        const float* xr = x + (size_t)row * 128 + kg * 8;
        #pragma unroll
        for (int s = 0; s < 4; ++s) {
            float4 xa = *(const float4*)(xr + s * 32);
            float4 xb = *(const float4*)(xr + s * 32 + 4);
            af[s].u[0] = bf16_rne(xa.x) | (bf16_rne(xa.y) << 16);
            af[s].u[1] = bf16_rne(xa.z) | (bf16_rne(xa.w) << 16);
            af[s].u[2] = bf16_rne(xb.x) | (bf16_rne(xb.y) << 16);
            af[s].u[3] = bf16_rne(xb.z) | (bf16_rne(xb.w) << 16);
        }

        f32x4 acc[8];
        #pragma unroll
        for (int tl = 0; tl < 8; ++tl) acc[tl] = (f32x4){0.f, 0.f, 0.f, 0.f};
        f32x4 accd = (f32x4){0.f, 0.f, 0.f, 0.f};

        #pragma unroll
        for (int s = 0; s < 4; ++s) {
            #pragma unroll
            for (int tl = 0; tl < 8; ++tl) {
                const bf16x8 bf = *(const bf16x8*)((char*)Wl
                    + (tl * 16 + col) * 272 + (s * 32 + kg * 8) * 2);
                acc[tl] = __builtin_amdgcn_mfma_f32_16x16x32_bf16(af[s].v, bf, acc[tl], 0, 0, 0);
            }
            accd = __builtin_amdgcn_mfma_f32_16x16x32_bf16(af[s].v, batt[s].v, accd, 0, 0, 0);
        }

        #pragma unroll
        for (int tl = 0; tl < 4; ++tl) {
            #pragma unroll
            for (int r = 0; r < 4; ++r) {
                int node = mb + kg * 4 + r;
                if (node < N) {
                    unsigned w = bf16_rne(acc[tl][r]) | (bf16_rne(acc[tl + 4][r]) << 16);
                    h2[(size_t)node * 64 + tl * 16 + col] = w;
                }
            }
        }
        if (col < 8) {
            float* bp = (col < 4) ? a_src : a_dst;
            const int j = col & 3;
            #pragma unroll
            for (int r = 0; r < 4; ++r) {
                int node = mb + kg * 4 + r;
                if (node < N) bp[(size_t)node * 4 + j] = accd[r];
            }
        }
    }
}

// ---- Kernel 2: one block per bucket. Pads each node's run to a multiple of
// 8 (pad: csr=n, alpha=0), derives rowse, sorts edges into padded csr,
// computes bf16 exps, per-node denominator via contiguous readback.
__global__ __launch_bounds__(256) void k_partC(
    const unsigned* __restrict__ stage, const int* __restrict__ gcur,
    const float* __restrict__ a_src, const float* __restrict__ a_dst,
    int2* __restrict__ rowse, int* __restrict__ csr,
    unsigned* __restrict__ alphaE, float* __restrict__ selfa,
    float* __restrict__ invD, int N, int cap)
{
    __shared__ int cnt[128];
    __shared__ int cur[128];
    __shared__ float adl[128][4];
    __shared__ int wtot;
    const int b = blockIdx.x, t = threadIdx.x;
    if (t < 128) {
        cnt[t] = 0;
        int n = (b << 7) + t;
        float4 v = (n < N) ? *(const float4*)(a_dst + (size_t)n * 4)
                           : make_float4(0.f, 0.f, 0.f, 0.f);
        *(float4*)adl[t] = v;
    }
    __syncthreads();
    const int slo = b * cap;
    const int ecnt = gcur[b];                 // relative count
    for (int e = t; e < ecnt; e += 256)
        atomicAdd(&cnt[stage[slo + e] >> 25], 1);
    __syncthreads();
    int v = 0, pv = 0, sc = 0, c0 = 0;
    const int l = t & 63;
    if (t < 128) {
        v = cnt[t];
        pv = (v + 7) & ~7;          // padded run length (multiple of 8)
        sc = pv;
        #pragma unroll
        for (int m = 1; m < 64; m <<= 1) {
            int u = __shfl_up(sc, m);
            if (l >= m) sc += u;
        }
        if (t == 63) wtot = sc;
    }
    __syncthreads();
    if (t < 128) {
        c0 = slo + sc - pv + ((t >= 64) ? wtot : 0);
        cur[t] = c0;
        int n = (b << 7) + t;
        if (n < N) rowse[n] = make_int2(c0, c0 + pv);
    }
    __syncthreads();
    for (int e = t; e < ecnt; e += 256) {
        unsigned u = stage[slo + e];
        int s  = (int)(u & 0x1FFFFFFu);
        int dl = (int)(u >> 25);
        float4 av = *(const float4*)(a_src + (size_t)s * 4);
        float x0 = LEXP(av.x + adl[dl][0]);
        float x1 = LEXP(av.y + adl[dl][1]);
        float x2 = LEXP(av.z + adl[dl][2]);
        float x3 = LEXP(av.w + adl[dl][3]);
        int pos = atomicAdd(&cur[dl], 1);
        csr[pos] = s;
        uint2 pk;
        pk.x = bf16_rne(x0) | (bf16_rne(x2) << 16);
        pk.y = bf16_rne(x1) | (bf16_rne(x3) << 16);
        *(uint2*)(alphaE + (size_t)pos * 2) = pk;
    }
    __syncthreads();
    if (t < 128) {
        int n = (b << 7) + t;
        if (n < N) {
            // pad entries: own row (L1-hot in k_agg), alpha = 0
            for (int i = c0 + v; i < c0 + pv; ++i) {
                csr[i] = n;
                *(uint2*)(alphaE + (size_t)i * 2) = make_uint2(0u, 0u);
            }
            // denominator: read back own contiguous alphaE run (L2-hot)
            float d0 = 0.f, d1 = 0.f, d2 = 0.f, d3 = 0.f;
            for (int i = c0; i < c0 + v; ++i) {
                uint2 pk = *(const uint2*)(alphaE + (size_t)i * 2);
                d0 += bf_lo(pk.x); d2 += bf_hi(pk.x);
                d1 += bf_lo(pk.y); d3 += bf_hi(pk.y);
            }
            float4 av = *(const float4*)(a_src + (size_t)n * 4);
            float p0 = LEXP(av.x + adl[t][0]);
            float p1 = LEXP(av.y + adl[t][1]);
            float p2 = LEXP(av.z + adl[t][2]);
            float p3 = LEXP(av.w + adl[t][3]);
            float i0 = 1.f / (d0 + p0);
            float i1 = 1.f / (d1 + p1);
            float i2 = 1.f / (d2 + p2);
            float i3 = 1.f / (d3 + p3);
            *(float4*)(selfa + (size_t)n * 4) = make_float4(p0 * i0, p1 * i1, p2 * i2, p3 * i3);
            *(float4*)(invD  + (size_t)n * 4) = make_float4(i0, i1, i2, i3);
        }
    }
}

// ---- Kernel 3: weighted gather-sum + fused classifier ----
// 128-thread blocks (2 waves). Padded runs: no clamping; tail = one 4-slot batch.
__global__ __launch_bounds__(128) void k_agg(
    const unsigned* __restrict__ h2, const unsigned* __restrict__ aP,
    const float* __restrict__ selfa, const float* __restrict__ invD,
    const int2* __restrict__ rowse, const int* __restrict__ csr,
    const float* __restrict__ b_gat, const float* __restrict__ W_lin,
    const float* __restrict__ b_lin, float* __restrict__ out, int N)
{
    const int t = threadIdx.x;
    const int wave = t >> 6, l = t & 63;
    const int n = blockIdx.x * 2 + wave;
    if (n >= N) return;

    const int m    = l & 31;
    const int half = l >> 5;
    const int c0   = 2 * m;
    const int hsel = m >> 4;
    const unsigned* aPh = aP + hsel;

    const int2 se = rowse[n];
    const int start = se.x, end = se.y;
    const float ivA = invD[n * 4 + hsel];
    const float ivB = invD[n * 4 + 2 + hsel];

    float a00 = 0.f, a01 = 0.f, a10 = 0.f, a11 = 0.f;

    int i = start;
    for (; i + 16 <= end; i += 16) {
        int sk[8]; unsigned d[8]; uint2 u[8];
        #pragma unroll
        for (int k = 0; k < 8; ++k) {
            int j = i + 2 * k + half;
            sk[k] = csr[j];
            d[k]  = aPh[(size_t)j * 2];
        }
        #pragma unroll
        for (int k = 0; k < 8; ++k)
            u[k] = *(const uint2*)(h2 + (size_t)sk[k] * 64 + c0);
        #pragma unroll
        for (int k = 0; k < 8; ++k) {
            float wl = bf_lo(d[k]), wh = bf_hi(d[k]);
            a00 += wl * bf_lo(u[k].x); a01 += wh * bf_hi(u[k].x);
            a10 += wl * bf_lo(u[k].y); a11 += wh * bf_hi(u[k].y);
        }
    }
    if (i < end) {                 // exactly 8 remaining (padded)
        int sk[4]; unsigned d[4]; uint2 u[4];
        #pragma unroll
        for (int k = 0; k < 4; ++k) {
            int j = i + 2 * k + half;
            sk[k] = csr[j];
            d[k]  = aPh[(size_t)j * 2];
        }
        #pragma unroll
        for (int k = 0; k < 4; ++k)
            u[k] = *(const uint2*)(h2 + (size_t)sk[k] * 64 + c0);
        #pragma unroll
        for (int k = 0; k < 4; ++k) {
            float wl = bf_lo(d[k]), wh = bf_hi(d[k]);
            a00 += wl * bf_lo(u[k].x); a01 += wh * bf_hi(u[k].x);
            a10 += wl * bf_lo(u[k].y); a11 += wh * bf_hi(u[k].y);
        }
    }

    a00 += __shfl_xor(a00, 32);
    a01 += __shfl_xor(a01, 32);
    a10 += __shfl_xor(a10, 32);
    a11 += __shfl_xor(a11, 32);
    a00 *= ivA; a01 *= ivB; a10 *= ivA; a11 *= ivB;

    {
        uint2 u = *(const uint2*)(h2 + (size_t)n * 64 + c0);
        float sA = selfa[n * 4 + hsel];
        float sB = selfa[n * 4 + 2 + hsel];
        a00 += sA * bf_lo(u.x); a01 += sB * bf_hi(u.x);
        a10 += sA * bf_lo(u.y); a11 += sB * bf_hi(u.y);
    }

    float r0 = fmaxf(a00 + b_gat[c0],      0.f);
    float r1 = fmaxf(a01 + b_gat[c0 + 64], 0.f);
    float r2 = fmaxf(a10 + b_gat[c0 + 1],  0.f);
    float r3 = fmaxf(a11 + b_gat[c0 + 65], 0.f);
    float p0 = r0 * W_lin[c0]       + r1 * W_lin[c0 + 64]
             + r2 * W_lin[c0 + 1]   + r3 * W_lin[c0 + 65];
    float p1 = r0 * W_lin[128 + c0]     + r1 * W_lin[128 + c0 + 64]
             + r2 * W_lin[128 + c0 + 1] + r3 * W_lin[128 + c0 + 65];
    #pragma unroll
    for (int s = 1; s < 32; s <<= 1) {
        p0 += __shfl_xor(p0, s);
        p1 += __shfl_xor(p1, s);
    }
    if (l == 0) {
        out[(size_t)n * 2]     = p0 + b_lin[0];
        out[(size_t)n * 2 + 1] = p1 + b_lin[1];
    }
}

// ---------------- launch ----------------
extern "C" void kernel_launch(void* const* d_in, const int* in_sizes, int n_in,
                              void* d_out, int out_size, void* d_ws, size_t ws_size,
                              hipStream_t stream)
{
    const float* x       = (const float*)d_in[0];
    const int*   ei      = (const int*)d_in[1];
    const float* Wg      = (const float*)d_in[2];
    const float* att_src = (const float*)d_in[3];
    const float* att_dst = (const float*)d_in[4];
    const float* b_gat   = (const float*)d_in[5];
    const float* W_lin   = (const float*)d_in[6];
    const float* b_lin   = (const float*)d_in[7];
    float* out = (float*)d_out;

    const int N = in_sizes[0] / 128;
    const int E = in_sizes[1] / 2;
    const int NBKT = (N + 127) >> 7;           // buckets of 128 nodes
    const int CAP  = 3328;                     // max bucket (+6sigma) + pad 896
    const int NBLKB = 256;
    const int CHUNK = (E + NBLKB - 1) / NBLKB; // <= 6272 (LDS dst cache)

    // workspace layout (padded csr/alphaE: bucket b at offset b*CAP)
    char* ws = (char*)d_ws;
    unsigned* h2  = (unsigned*)ws;                    // N*64 packed bf16x2
    float* a_src  = (float*)(h2 + (size_t)N * 64);    // N*4
    float* a_dst  = a_src + (size_t)N * 4;            // N*4
    float* selfa  = a_dst + (size_t)N * 4;            // N*4
    float* invD   = selfa + (size_t)N * 4;            // N*4
    int2*  rowse  = (int2*)(invD + (size_t)N * 4);    // N int2
    int*   csr    = (int*)(rowse + N);                // NBKT*CAP
    unsigned* alphaE = (unsigned*)(csr + (size_t)NBKT * CAP); // NBKT*CAP*2
    unsigned* stage  = alphaE + (size_t)NBKT * CAP * 2;       // NBKT*CAP
    int*   gcur   = (int*)(stage + (size_t)NBKT * CAP);       // NBKT

    hipMemsetAsync(gcur, 0, (size_t)NBKT * sizeof(int), stream);
    k_gemm_partB<<<512 + NBLKB, 256, 0, stream>>>(
        x, Wg, att_src, att_dst, h2, a_src, a_dst, N,
        ei, gcur, stage, E, NBKT, CAP, CHUNK);
    k_partC<<<NBKT, 256, 0, stream>>>(stage, gcur, a_src, a_dst, rowse, csr,
                                      alphaE, selfa, invD, N, CAP);
    k_agg<<<(N + 1) / 2, 128, 0, stream>>>(h2, alphaE, selfa, invD, rowse, csr,
                                           b_gat, W_lin, b_lin, out, N);
}

// Round 16
// 164.055 us; speedup vs baseline: 1.0694x; 1.0694x over previous
//
#include <hip/hip_runtime.h>

#define NSLOPE  0.2f
#define LEXP(v) __expf((v) >= 0.f ? (v) : NSLOPE * (v))

typedef __attribute__((ext_vector_type(8))) short bf16x8;
typedef __attribute__((ext_vector_type(4))) float f32x4;

__device__ __forceinline__ unsigned bf16_rne(float f) {
    unsigned x = __float_as_uint(f);
    return (x + 0x7fffu + ((x >> 16) & 1u)) >> 16;
}
__device__ __forceinline__ float bf_lo(unsigned u) { return __uint_as_float(u << 16); }
__device__ __forceinline__ float bf_hi(unsigned u) { return __uint_as_float(u & 0xffff0000u); }

// ---- Kernel 1: blocks [0,512): h2 = bf16(x@W^T) via MFMA + att dots via
// 4 extra MFMAs against watt = att@W. Block 512: init gcur[b] = b*CAP.
__global__ __launch_bounds__(256) void k_gemm_init(
    const float* __restrict__ x, const float* __restrict__ Wg,
    const float* __restrict__ att_src, const float* __restrict__ att_dst,
    unsigned* __restrict__ h2, float* __restrict__ a_src, float* __restrict__ a_dst,
    int N, int* __restrict__ gcur, int nbkt, int cap)
{
    __shared__ unsigned short Wl[128 * 136];   // bf16 W (34.8KB)
    __shared__ unsigned short wattH[8][128];   // bf16 watt (2KB)

    const int t = threadIdx.x;

    if (blockIdx.x >= 512) {                   // ---- gcur init role ----
        for (int i = t; i < nbkt; i += 256) gcur[i] = i * cap;
        return;
    }

    // ---- GEMM role ----
    for (int i = t; i < 128 * 32; i += 256) {
        int r = i >> 5, c4 = (i & 31) * 4;
        float4 w = *(const float4*)(Wg + r * 128 + c4);
        unsigned* wp = (unsigned*)((char*)Wl + r * 272 + c4 * 2);
        wp[0] = bf16_rne(w.x) | (bf16_rne(w.y) << 16);
        wp[1] = bf16_rne(w.z) | (bf16_rne(w.w) << 16);
    }
    // watt[j][f]: j<4 -> src head j; j>=4 -> dst head j-4
    for (int idx = t; idx < 1024; idx += 256) {
        int j = idx >> 7, f = idx & 127;
        const float* av = (j < 4) ? (att_src + j * 32) : (att_dst + (j - 4) * 32);
        int hh = (j & 3) * 32;
        float s = 0.f;
        #pragma unroll 8
        for (int k = 0; k < 32; ++k)
            s += av[k] * Wg[(size_t)(hh + k) * 128 + f];
        wattH[j][f] = (unsigned short)bf16_rne(s);
    }
    __syncthreads();

    const int wave = t >> 6, l = t & 63;
    const int col = l & 15, kg = l >> 4;

    union { bf16x8 v; unsigned short s[8]; } batt[4];
    #pragma unroll
    for (int s4 = 0; s4 < 4; ++s4) {
        #pragma unroll
        for (int jj = 0; jj < 8; ++jj)
            batt[s4].s[jj] = (col < 8) ? wattH[col][s4 * 32 + kg * 8 + jj]
                                       : (unsigned short)0;
    }

    const int nwaves = 512 * 4;
    const int wid = blockIdx.x * 4 + wave;

    for (int mb = wid * 16; mb < N; mb += nwaves * 16) {
        union { bf16x8 v; unsigned u[4]; } af[4];
        int row = mb + col; if (row >= N) row = N - 1;
        const float* xr = x + (size_t)row * 128 + kg * 8;
        #pragma unroll
        for (int s = 0; s < 4; ++s) {
            float4 xa = *(const float4*)(xr + s * 32);
            float4 xb = *(const float4*)(xr + s * 32 + 4);
            af[s].u[0] = bf16_rne(xa.x) | (bf16_rne(xa.y) << 16);
            af[s].u[1] = bf16_rne(xa.z) | (bf16_rne(xa.w) << 16);
            af[s].u[2] = bf16_rne(xb.x) | (bf16_rne(xb.y) << 16);
            af[s].u[3] = bf16_rne(xb.z) | (bf16_rne(xb.w) << 16);
        }

        f32x4 acc[8];
        #pragma unroll
        for (int tl = 0; tl < 8; ++tl) acc[tl] = (f32x4){0.f, 0.f, 0.f, 0.f};
        f32x4 accd = (f32x4){0.f, 0.f, 0.f, 0.f};

        #pragma unroll
        for (int s = 0; s < 4; ++s) {
            #pragma unroll
            for (int tl = 0; tl < 8; ++tl) {
                const bf16x8 bf = *(const bf16x8*)((char*)Wl
                    + (tl * 16 + col) * 272 + (s * 32 + kg * 8) * 2);
                acc[tl] = __builtin_amdgcn_mfma_f32_16x16x32_bf16(af[s].v, bf, acc[tl], 0, 0, 0);
            }
            accd = __builtin_amdgcn_mfma_f32_16x16x32_bf16(af[s].v, batt[s].v, accd, 0, 0, 0);
        }

        #pragma unroll
        for (int tl = 0; tl < 4; ++tl) {
            #pragma unroll
            for (int r = 0; r < 4; ++r) {
                int node = mb + kg * 4 + r;
                if (node < N) {
                    unsigned w = bf16_rne(acc[tl][r]) | (bf16_rne(acc[tl + 4][r]) << 16);
                    h2[(size_t)node * 64 + tl * 16 + col] = w;
                }
            }
        }
        if (col < 8) {
            float* bp = (col < 4) ? a_src : a_dst;
            const int j = col & 3;
            #pragma unroll
            for (int r = 0; r < 4; ++r) {
                int node = mb + kg * 4 + r;
                if (node < N) bp[(size_t)node * 4 + j] = accd[r];
            }
        }
    }
}

// ---- Kernel 2: fused count + reserve + scatter into padded bucket regions.
// Buckets of 64 nodes: bucket = d>>6, dlow = d&63 packed at bit 26.
__global__ __launch_bounds__(256) void k_partB2(
    const int* __restrict__ ei, int* __restrict__ gcur,
    unsigned* __restrict__ stage, int E, int nbkt, int chunk)
{
    __shared__ int dstc[6272];
    __shared__ int lcnt[1600];
    __shared__ int lbase[1600];
    const int t = threadIdx.x;
    for (int i = t; i < nbkt; i += 256) lcnt[i] = 0;
    __syncthreads();
    const int lo = blockIdx.x * chunk, hi = min(lo + chunk, E);
    for (int e = lo + t; e < hi; e += 256) {
        int d = ei[E + e];
        dstc[e - lo] = d;
        atomicAdd(&lcnt[d >> 6], 1);
    }
    __syncthreads();
    for (int i = t; i < nbkt; i += 256) {
        int c = lcnt[i];
        lbase[i] = (c > 0) ? atomicAdd(&gcur[i], c) : 0;
    }
    __syncthreads();
    for (int e = lo + t; e < hi; e += 256) {
        int s = ei[e];
        int d = dstc[e - lo];
        int pos = atomicAdd(&lbase[d >> 6], 1);
        stage[pos] = (unsigned)s | ((unsigned)(d & 63) << 26);
    }
}

// ---- Kernel 3: one block per 64-node bucket. Pads each node's run to a
// multiple of 8 (pad: csr=n, alpha=0), derives rowse, sorts edges into
// padded csr, computes bf16 exps, denominator via contiguous readback.
__global__ __launch_bounds__(256) void k_partC(
    const unsigned* __restrict__ stage, const int* __restrict__ gcur,
    const float* __restrict__ a_src, const float* __restrict__ a_dst,
    int2* __restrict__ rowse, int* __restrict__ csr,
    unsigned* __restrict__ alphaE, float* __restrict__ selfa,
    float* __restrict__ invD, int N, int cap)
{
    __shared__ int cnt[64];
    __shared__ int cur[64];
    __shared__ float adl[64][4];
    const int b = blockIdx.x, t = threadIdx.x;
    if (t < 64) {
        cnt[t] = 0;
        int n = (b << 6) + t;
        float4 v = (n < N) ? *(const float4*)(a_dst + (size_t)n * 4)
                           : make_float4(0.f, 0.f, 0.f, 0.f);
        *(float4*)adl[t] = v;
    }
    __syncthreads();
    const int slo = b * cap;
    const int ecnt = gcur[b] - slo;
    for (int e = t; e < ecnt; e += 256)
        atomicAdd(&cnt[stage[slo + e] >> 26], 1);
    __syncthreads();
    int v = 0, pv = 0, c0 = 0;
    if (t < 64) {                   // single-wave scan over 64 node counts
        v = cnt[t];
        pv = (v + 7) & ~7;          // padded run length (multiple of 8)
        int sc = pv;
        #pragma unroll
        for (int m = 1; m < 64; m <<= 1) {
            int u = __shfl_up(sc, m);
            if (t >= m) sc += u;
        }
        c0 = slo + sc - pv;
        cur[t] = c0;
        int n = (b << 6) + t;
        if (n < N) rowse[n] = make_int2(c0, c0 + pv);
    }
    __syncthreads();
    for (int e = t; e < ecnt; e += 256) {
        unsigned u = stage[slo + e];
        int s  = (int)(u & 0x3FFFFFFu);
        int dl = (int)(u >> 26);
        float4 av = *(const float4*)(a_src + (size_t)s * 4);
        float x0 = LEXP(av.x + adl[dl][0]);
        float x1 = LEXP(av.y + adl[dl][1]);
        float x2 = LEXP(av.z + adl[dl][2]);
        float x3 = LEXP(av.w + adl[dl][3]);
        int pos = atomicAdd(&cur[dl], 1);
        csr[pos] = s;
        uint2 pk;
        pk.x = bf16_rne(x0) | (bf16_rne(x2) << 16);
        pk.y = bf16_rne(x1) | (bf16_rne(x3) << 16);
        *(uint2*)(alphaE + (size_t)pos * 2) = pk;
    }
    __syncthreads();
    if (t < 64) {
        int n = (b << 6) + t;
        if (n < N) {
            // pad entries: own row (L1-hot in k_agg), alpha = 0
            for (int i = c0 + v; i < c0 + pv; ++i) {
                csr[i] = n;
                *(uint2*)(alphaE + (size_t)i * 2) = make_uint2(0u, 0u);
            }
            // denominator: read back own contiguous alphaE run (L2-hot)
            float d0 = 0.f, d1 = 0.f, d2 = 0.f, d3 = 0.f;
            for (int i = c0; i < c0 + v; ++i) {
                uint2 pk = *(const uint2*)(alphaE + (size_t)i * 2);
                d0 += bf_lo(pk.x); d2 += bf_hi(pk.x);
                d1 += bf_lo(pk.y); d3 += bf_hi(pk.y);
            }
            float4 av = *(const float4*)(a_src + (size_t)n * 4);
            float p0 = LEXP(av.x + adl[t][0]);
            float p1 = LEXP(av.y + adl[t][1]);
            float p2 = LEXP(av.z + adl[t][2]);
            float p3 = LEXP(av.w + adl[t][3]);
            float i0 = 1.f / (d0 + p0);
            float i1 = 1.f / (d1 + p1);
            float i2 = 1.f / (d2 + p2);
            float i3 = 1.f / (d3 + p3);
            *(float4*)(selfa + (size_t)n * 4) = make_float4(p0 * i0, p1 * i1, p2 * i2, p3 * i3);
            *(float4*)(invD  + (size_t)n * 4) = make_float4(i0, i1, i2, i3);
        }
    }
}

// ---- Kernel 4: weighted gather-sum + fused classifier ----
// 128-thread blocks (2 waves). Padded runs: no clamping; tail = one 4-slot batch.
__global__ __launch_bounds__(128) void k_agg(
    const unsigned* __restrict__ h2, const unsigned* __restrict__ aP,
    const float* __restrict__ selfa, const float* __restrict__ invD,
    const int2* __restrict__ rowse, const int* __restrict__ csr,
    const float* __restrict__ b_gat, const float* __restrict__ W_lin,
    const float* __restrict__ b_lin, float* __restrict__ out, int N)
{
    const int t = threadIdx.x;
    const int wave = t >> 6, l = t & 63;
    const int n = blockIdx.x * 2 + wave;
    if (n >= N) return;

    const int m    = l & 31;
    const int half = l >> 5;
    const int c0   = 2 * m;
    const int hsel = m >> 4;
    const unsigned* aPh = aP + hsel;

    const int2 se = rowse[n];
    const int start = se.x, end = se.y;
    const float ivA = invD[n * 4 + hsel];
    const float ivB = invD[n * 4 + 2 + hsel];

    float a00 = 0.f, a01 = 0.f, a10 = 0.f, a11 = 0.f;

    int i = start;
    for (; i + 16 <= end; i += 16) {
        int sk[8]; unsigned d[8]; uint2 u[8];
        #pragma unroll
        for (int k = 0; k < 8; ++k) {
            int j = i + 2 * k + half;
            sk[k] = csr[j];
            d[k]  = aPh[(size_t)j * 2];
        }
        #pragma unroll
        for (int k = 0; k < 8; ++k)
            u[k] = *(const uint2*)(h2 + (size_t)sk[k] * 64 + c0);
        #pragma unroll
        for (int k = 0; k < 8; ++k) {
            float wl = bf_lo(d[k]), wh = bf_hi(d[k]);
            a00 += wl * bf_lo(u[k].x); a01 += wh * bf_hi(u[k].x);
            a10 += wl * bf_lo(u[k].y); a11 += wh * bf_hi(u[k].y);
        }
    }
    if (i < end) {                 // exactly 8 remaining (padded)
        int sk[4]; unsigned d[4]; uint2 u[4];
        #pragma unroll
        for (int k = 0; k < 4; ++k) {
            int j = i + 2 * k + half;
            sk[k] = csr[j];
            d[k]  = aPh[(size_t)j * 2];
        }
        #pragma unroll
        for (int k = 0; k < 4; ++k)
            u[k] = *(const uint2*)(h2 + (size_t)sk[k] * 64 + c0);
        #pragma unroll
        for (int k = 0; k < 4; ++k) {
            float wl = bf_lo(d[k]), wh = bf_hi(d[k]);
            a00 += wl * bf_lo(u[k].x); a01 += wh * bf_hi(u[k].x);
            a10 += wl * bf_lo(u[k].y); a11 += wh * bf_hi(u[k].y);
        }
    }

    a00 += __shfl_xor(a00, 32);
    a01 += __shfl_xor(a01, 32);
    a10 += __shfl_xor(a10, 32);
    a11 += __shfl_xor(a11, 32);
    a00 *= ivA; a01 *= ivB; a10 *= ivA; a11 *= ivB;

    {
        uint2 u = *(const uint2*)(h2 + (size_t)n * 64 + c0);
        float sA = selfa[n * 4 + hsel];
        float sB = selfa[n * 4 + 2 + hsel];
        a00 += sA * bf_lo(u.x); a01 += sB * bf_hi(u.x);
        a10 += sA * bf_lo(u.y); a11 += sB * bf_hi(u.y);
    }

    float r0 = fmaxf(a00 + b_gat[c0],      0.f);
    float r1 = fmaxf(a01 + b_gat[c0 + 64], 0.f);
    float r2 = fmaxf(a10 + b_gat[c0 + 1],  0.f);
    float r3 = fmaxf(a11 + b_gat[c0 + 65], 0.f);
    float p0 = r0 * W_lin[c0]       + r1 * W_lin[c0 + 64]
             + r2 * W_lin[c0 + 1]   + r3 * W_lin[c0 + 65];
    float p1 = r0 * W_lin[128 + c0]     + r1 * W_lin[128 + c0 + 64]
             + r2 * W_lin[128 + c0 + 1] + r3 * W_lin[128 + c0 + 65];
    #pragma unroll
    for (int s = 1; s < 32; s <<= 1) {
        p0 += __shfl_xor(p0, s);
        p1 += __shfl_xor(p1, s);
    }
    if (l == 0) {
        out[(size_t)n * 2]     = p0 + b_lin[0];
        out[(size_t)n * 2 + 1] = p1 + b_lin[1];
    }
}

// ---------------- launch ----------------
extern "C" void kernel_launch(void* const* d_in, const int* in_sizes, int n_in,
                              void* d_out, int out_size, void* d_ws, size_t ws_size,
                              hipStream_t stream)
{
    const float* x       = (const float*)d_in[0];
    const int*   ei      = (const int*)d_in[1];
    const float* Wg      = (const float*)d_in[2];
    const float* att_src = (const float*)d_in[3];
    const float* att_dst = (const float*)d_in[4];
    const float* b_gat   = (const float*)d_in[5];
    const float* W_lin   = (const float*)d_in[6];
    const float* b_lin   = (const float*)d_in[7];
    float* out = (float*)d_out;

    const int N = in_sizes[0] / 128;
    const int E = in_sizes[1] / 2;
    const int NBKT = (N + 63) >> 6;            // buckets of 64 nodes (<=1600)
    const int CAP  = 1728;                     // max bucket (~1240) + pad (<=448)
    const int NBLKB = 256;
    const int CHUNK = (E + NBLKB - 1) / NBLKB; // <= 6272 (LDS dst cache)

    // workspace layout (padded csr/alphaE: bucket b at offset b*CAP)
    char* ws = (char*)d_ws;
    unsigned* h2  = (unsigned*)ws;                    // N*64 packed bf16x2
    float* a_src  = (float*)(h2 + (size_t)N * 64);    // N*4
    float* a_dst  = a_src + (size_t)N * 4;            // N*4
    float* selfa  = a_dst + (size_t)N * 4;            // N*4
    float* invD   = selfa + (size_t)N * 4;            // N*4
    int2*  rowse  = (int2*)(invD + (size_t)N * 4);    // N int2
    int*   csr    = (int*)(rowse + N);                // NBKT*CAP
    unsigned* alphaE = (unsigned*)(csr + (size_t)NBKT * CAP); // NBKT*CAP*2
    unsigned* stage  = alphaE + (size_t)NBKT * CAP * 2;       // NBKT*CAP
    int*   gcur   = (int*)(stage + (size_t)NBKT * CAP);       // NBKT

    k_gemm_init<<<513, 256, 0, stream>>>(
        x, Wg, att_src, att_dst, h2, a_src, a_dst, N, gcur, NBKT, CAP);
    k_partB2<<<NBLKB, 256, 0, stream>>>(ei, gcur, stage, E, NBKT, CHUNK);
    k_partC<<<NBKT, 256, 0, stream>>>(stage, gcur, a_src, a_dst, rowse, csr,
                                      alphaE, selfa, invD, N, CAP);
    k_agg<<<(N + 1) / 2, 128, 0, stream>>>(h2, alphaE, selfa, invD, rowse, csr,
                                           b_gat, W_lin, b_lin, out, N);
}

// Round 17
// 142.005 us; speedup vs baseline: 1.2355x; 1.1553x over previous
//
#include <hip/hip_runtime.h>

#define NSLOPE  0.2f
#define LEXP(v) __expf((v) >= 0.f ? (v) : NSLOPE * (v))

typedef __attribute__((ext_vector_type(8))) short bf16x8;
typedef __attribute__((ext_vector_type(4))) float f32x4;

__device__ __forceinline__ unsigned bf16_rne(float f) {
    unsigned x = __float_as_uint(f);
    return (x + 0x7fffu + ((x >> 16) & 1u)) >> 16;
}
__device__ __forceinline__ float bf_lo(unsigned u) { return __uint_as_float(u << 16); }
__device__ __forceinline__ float bf_hi(unsigned u) { return __uint_as_float(u & 0xffff0000u); }

// ---- Kernel 1: blocks [0,512): h2 = bf16(x@W^T) via MFMA + att dots via
// 4 extra MFMAs against watt = att@W. Block 512: init gcur[b] = b*CAP.
__global__ __launch_bounds__(256) void k_gemm_init(
    const float* __restrict__ x, const float* __restrict__ Wg,
    const float* __restrict__ att_src, const float* __restrict__ att_dst,
    unsigned* __restrict__ h2, float* __restrict__ a_src, float* __restrict__ a_dst,
    int N, int* __restrict__ gcur, int nbkt, int cap)
{
    __shared__ unsigned short Wl[128 * 136];   // bf16 W (34.8KB)
    __shared__ unsigned short wattH[8][128];   // bf16 watt (2KB)

    const int t = threadIdx.x;

    if (blockIdx.x >= 512) {                   // ---- gcur init role ----
        for (int i = t; i < nbkt; i += 256) gcur[i] = i * cap;
        return;
    }

    // ---- GEMM role ----
    for (int i = t; i < 128 * 32; i += 256) {
        int r = i >> 5, c4 = (i & 31) * 4;
        float4 w = *(const float4*)(Wg + r * 128 + c4);
        unsigned* wp = (unsigned*)((char*)Wl + r * 272 + c4 * 2);
        wp[0] = bf16_rne(w.x) | (bf16_rne(w.y) << 16);
        wp[1] = bf16_rne(w.z) | (bf16_rne(w.w) << 16);
    }
    // watt[j][f]: j<4 -> src head j; j>=4 -> dst head j-4
    for (int idx = t; idx < 1024; idx += 256) {
        int j = idx >> 7, f = idx & 127;
        const float* av = (j < 4) ? (att_src + j * 32) : (att_dst + (j - 4) * 32);
        int hh = (j & 3) * 32;
        float s = 0.f;
        #pragma unroll 8
        for (int k = 0; k < 32; ++k)
            s += av[k] * Wg[(size_t)(hh + k) * 128 + f];
        wattH[j][f] = (unsigned short)bf16_rne(s);
    }
    __syncthreads();

    const int wave = t >> 6, l = t & 63;
    const int col = l & 15, kg = l >> 4;

    union { bf16x8 v; unsigned short s[8]; } batt[4];
    #pragma unroll
    for (int s4 = 0; s4 < 4; ++s4) {
        #pragma unroll
        for (int jj = 0; jj < 8; ++jj)
            batt[s4].s[jj] = (col < 8) ? wattH[col][s4 * 32 + kg * 8 + jj]
                                       : (unsigned short)0;
    }

    const int nwaves = 512 * 4;
    const int wid = blockIdx.x * 4 + wave;

    for (int mb = wid * 16; mb < N; mb += nwaves * 16) {
        union { bf16x8 v; unsigned u[4]; } af[4];
        int row = mb + col; if (row >= N) row = N - 1;
        const float* xr = x + (size_t)row * 128 + kg * 8;
        #pragma unroll
        for (int s = 0; s < 4; ++s) {
            float4 xa = *(const float4*)(xr + s * 32);
            float4 xb = *(const float4*)(xr + s * 32 + 4);
            af[s].u[0] = bf16_rne(xa.x) | (bf16_rne(xa.y) << 16);
            af[s].u[1] = bf16_rne(xa.z) | (bf16_rne(xa.w) << 16);
            af[s].u[2] = bf16_rne(xb.x) | (bf16_rne(xb.y) << 16);
            af[s].u[3] = bf16_rne(xb.z) | (bf16_rne(xb.w) << 16);
        }

        f32x4 acc[8];
        #pragma unroll
        for (int tl = 0; tl < 8; ++tl) acc[tl] = (f32x4){0.f, 0.f, 0.f, 0.f};
        f32x4 accd = (f32x4){0.f, 0.f, 0.f, 0.f};

        #pragma unroll
        for (int s = 0; s < 4; ++s) {
            #pragma unroll
            for (int tl = 0; tl < 8; ++tl) {
                const bf16x8 bf = *(const bf16x8*)((char*)Wl
                    + (tl * 16 + col) * 272 + (s * 32 + kg * 8) * 2);
                acc[tl] = __builtin_amdgcn_mfma_f32_16x16x32_bf16(af[s].v, bf, acc[tl], 0, 0, 0);
            }
            accd = __builtin_amdgcn_mfma_f32_16x16x32_bf16(af[s].v, batt[s].v, accd, 0, 0, 0);
        }

        #pragma unroll
        for (int tl = 0; tl < 4; ++tl) {
            #pragma unroll
            for (int r = 0; r < 4; ++r) {
                int node = mb + kg * 4 + r;
                if (node < N) {
                    unsigned w = bf16_rne(acc[tl][r]) | (bf16_rne(acc[tl + 4][r]) << 16);
                    h2[(size_t)node * 64 + tl * 16 + col] = w;
                }
            }
        }
        if (col < 8) {
            float* bp = (col < 4) ? a_src : a_dst;
            const int j = col & 3;
            #pragma unroll
            for (int r = 0; r < 4; ++r) {
                int node = mb + kg * 4 + r;
                if (node < N) bp[(size_t)node * 4 + j] = accd[r];
            }
        }
    }
}

// ---- Kernel 2: fused count + reserve + scatter into padded bucket regions.
// Buckets of 64 nodes: bucket = d>>6, dlow = d&63 packed at bit 26.
__global__ __launch_bounds__(256) void k_partB2(
    const int* __restrict__ ei, int* __restrict__ gcur,
    unsigned* __restrict__ stage, int E, int nbkt, int chunk)
{
    __shared__ int dstc[6272];
    __shared__ int lcnt[1600];
    __shared__ int lbase[1600];
    const int t = threadIdx.x;
    for (int i = t; i < nbkt; i += 256) lcnt[i] = 0;
    __syncthreads();
    const int lo = blockIdx.x * chunk, hi = min(lo + chunk, E);
    for (int e = lo + t; e < hi; e += 256) {
        int d = ei[E + e];
        dstc[e - lo] = d;
        atomicAdd(&lcnt[d >> 6], 1);
    }
    __syncthreads();
    for (int i = t; i < nbkt; i += 256) {
        int c = lcnt[i];
        lbase[i] = (c > 0) ? atomicAdd(&gcur[i], c) : 0;
    }
    __syncthreads();
    for (int e = lo + t; e < hi; e += 256) {
        int s = ei[e];
        int d = dstc[e - lo];
        int pos = atomicAdd(&lbase[d >> 6], 1);
        stage[pos] = (unsigned)s | ((unsigned)(d & 63) << 26);
    }
}

// ---- Kernel 3 (fused partC + agg): one block per 64-node bucket.
// Phase 1-5: count, scan, scatter edges into LDS (computing bf16 exps from
// L2-resident a_src gathers), pad runs to multiples of 8, per-node
// denominators via LDS readback. Phase 6: k_agg aggregation loop with edge
// metadata served from LDS; h2 gathers from global; fused classifier.
__global__ __launch_bounds__(256) void k_aggC(
    const unsigned* __restrict__ stage, const int* __restrict__ gcur,
    const float* __restrict__ a_src, const float* __restrict__ a_dst,
    const unsigned* __restrict__ h2, const float* __restrict__ b_gat,
    const float* __restrict__ W_lin, const float* __restrict__ b_lin,
    float* __restrict__ out, int N, int cap)
{
    __shared__ int      eS[1728];
    __shared__ unsigned eA0[1728];
    __shared__ unsigned eA1[1728];
    __shared__ int cnt[64];
    __shared__ int cur[64];
    __shared__ int rs[64];
    __shared__ int re[64];
    __shared__ float adl[64][4];
    __shared__ float selfaL[64][4];
    __shared__ float invDL[64][4];

    const int b = blockIdx.x, t = threadIdx.x;
    const int wave = t >> 6, l = t & 63;

    if (t < 64) {
        cnt[t] = 0;
        int n = (b << 6) + t;
        float4 v = (n < N) ? *(const float4*)(a_dst + (size_t)n * 4)
                           : make_float4(0.f, 0.f, 0.f, 0.f);
        *(float4*)adl[t] = v;
    }
    __syncthreads();
    const int slo = b * cap;
    const int ecnt = gcur[b] - slo;
    for (int e = t; e < ecnt; e += 256)
        atomicAdd(&cnt[stage[slo + e] >> 26], 1);
    __syncthreads();
    if (t < 64) {                   // single-wave scan (wave 0)
        int v = cnt[t];
        int pv = (v + 7) & ~7;      // padded run length
        int sc = pv;
        #pragma unroll
        for (int m = 1; m < 64; m <<= 1) {
            int u = __shfl_up(sc, m);
            if (t >= m) sc += u;
        }
        int c0 = sc - pv;           // LDS-local offset
        cur[t] = c0;
        rs[t] = c0; re[t] = c0 + pv;
    }
    __syncthreads();
    for (int e = t; e < ecnt; e += 256) {
        unsigned u = stage[slo + e];
        int s  = (int)(u & 0x3FFFFFFu);
        int dl = (int)(u >> 26);
        float4 av = *(const float4*)(a_src + (size_t)s * 4);
        float x0 = LEXP(av.x + adl[dl][0]);
        float x1 = LEXP(av.y + adl[dl][1]);
        float x2 = LEXP(av.z + adl[dl][2]);
        float x3 = LEXP(av.w + adl[dl][3]);
        int pos = atomicAdd(&cur[dl], 1);
        eS[pos]  = s;
        eA0[pos] = bf16_rne(x0) | (bf16_rne(x2) << 16);
        eA1[pos] = bf16_rne(x1) | (bf16_rne(x3) << 16);
    }
    __syncthreads();
    if (t < 64) {
        int n = (b << 6) + t;
        if (n < N) {
            const int c0 = rs[t], e1 = cur[t], pe = re[t];
            for (int i = e1; i < pe; ++i) {   // pad: own row, alpha 0
                eS[i] = n; eA0[i] = 0u; eA1[i] = 0u;
            }
            float d0 = 0.f, d1 = 0.f, d2 = 0.f, d3 = 0.f;
            for (int i = c0; i < e1; ++i) {
                unsigned p0 = eA0[i], p1 = eA1[i];
                d0 += bf_lo(p0); d2 += bf_hi(p0);
                d1 += bf_lo(p1); d3 += bf_hi(p1);
            }
            float4 av = *(const float4*)(a_src + (size_t)n * 4);
            float p0 = LEXP(av.x + adl[t][0]);
            float p1 = LEXP(av.y + adl[t][1]);
            float p2 = LEXP(av.z + adl[t][2]);
            float p3 = LEXP(av.w + adl[t][3]);
            float i0 = 1.f / (d0 + p0);
            float i1 = 1.f / (d1 + p1);
            float i2 = 1.f / (d2 + p2);
            float i3 = 1.f / (d3 + p3);
            selfaL[t][0] = p0 * i0; selfaL[t][1] = p1 * i1;
            selfaL[t][2] = p2 * i2; selfaL[t][3] = p3 * i3;
            invDL[t][0] = i0; invDL[t][1] = i1;
            invDL[t][2] = i2; invDL[t][3] = i3;
        }
    }
    __syncthreads();

    // ---- aggregation: wave w handles local nodes w, w+4, ... ----
    const int m    = l & 31;
    const int half = l >> 5;
    const int cch  = 2 * m;
    const int hsel = m >> 4;
    const unsigned* eAh = hsel ? eA1 : eA0;

    for (int ln = wave; ln < 64; ln += 4) {
        int n = (b << 6) + ln;
        if (n >= N) break;
        const int start = rs[ln], end = re[ln];
        float a00 = 0.f, a01 = 0.f, a10 = 0.f, a11 = 0.f;

        int i = start;
        for (; i + 16 <= end; i += 16) {
            int sk[8]; unsigned d[8]; uint2 u[8];
            #pragma unroll
            for (int k = 0; k < 8; ++k) {
                int j = i + 2 * k + half;
                sk[k] = eS[j];
                d[k]  = eAh[j];
            }
            #pragma unroll
            for (int k = 0; k < 8; ++k)
                u[k] = *(const uint2*)(h2 + (size_t)sk[k] * 64 + cch);
            #pragma unroll
            for (int k = 0; k < 8; ++k) {
                float wl = bf_lo(d[k]), wh = bf_hi(d[k]);
                a00 += wl * bf_lo(u[k].x); a01 += wh * bf_hi(u[k].x);
                a10 += wl * bf_lo(u[k].y); a11 += wh * bf_hi(u[k].y);
            }
        }
        if (i < end) {               // exactly 8 remaining (padded)
            int sk[4]; unsigned d[4]; uint2 u[4];
            #pragma unroll
            for (int k = 0; k < 4; ++k) {
                int j = i + 2 * k + half;
                sk[k] = eS[j];
                d[k]  = eAh[j];
            }
            #pragma unroll
            for (int k = 0; k < 4; ++k)
                u[k] = *(const uint2*)(h2 + (size_t)sk[k] * 64 + cch);
            #pragma unroll
            for (int k = 0; k < 4; ++k) {
                float wl = bf_lo(d[k]), wh = bf_hi(d[k]);
                a00 += wl * bf_lo(u[k].x); a01 += wh * bf_hi(u[k].x);
                a10 += wl * bf_lo(u[k].y); a11 += wh * bf_hi(u[k].y);
            }
        }

        a00 += __shfl_xor(a00, 32);
        a01 += __shfl_xor(a01, 32);
        a10 += __shfl_xor(a10, 32);
        a11 += __shfl_xor(a11, 32);
        const float ivA = invDL[ln][hsel], ivB = invDL[ln][2 + hsel];
        a00 *= ivA; a01 *= ivB; a10 *= ivA; a11 *= ivB;

        {
            uint2 u = *(const uint2*)(h2 + (size_t)n * 64 + cch);
            float sA = selfaL[ln][hsel], sB = selfaL[ln][2 + hsel];
            a00 += sA * bf_lo(u.x); a01 += sB * bf_hi(u.x);
            a10 += sA * bf_lo(u.y); a11 += sB * bf_hi(u.y);
        }

        float r0 = fmaxf(a00 + b_gat[cch],      0.f);
        float r1 = fmaxf(a01 + b_gat[cch + 64], 0.f);
        float r2 = fmaxf(a10 + b_gat[cch + 1],  0.f);
        float r3 = fmaxf(a11 + b_gat[cch + 65], 0.f);
        float p0 = r0 * W_lin[cch]       + r1 * W_lin[cch + 64]
                 + r2 * W_lin[cch + 1]   + r3 * W_lin[cch + 65];
        float p1 = r0 * W_lin[128 + cch]     + r1 * W_lin[128 + cch + 64]
                 + r2 * W_lin[128 + cch + 1] + r3 * W_lin[128 + cch + 65];
        #pragma unroll
        for (int s = 1; s < 32; s <<= 1) {
            p0 += __shfl_xor(p0, s);
            p1 += __shfl_xor(p1, s);
        }
        if (l == 0) {
            out[(size_t)n * 2]     = p0 + b_lin[0];
            out[(size_t)n * 2 + 1] = p1 + b_lin[1];
        }
    }
}

// ---------------- launch ----------------
extern "C" void kernel_launch(void* const* d_in, const int* in_sizes, int n_in,
                              void* d_out, int out_size, void* d_ws, size_t ws_size,
                              hipStream_t stream)
{
    const float* x       = (const float*)d_in[0];
    const int*   ei      = (const int*)d_in[1];
    const float* Wg      = (const float*)d_in[2];
    const float* att_src = (const float*)d_in[3];
    const float* att_dst = (const float*)d_in[4];
    const float* b_gat   = (const float*)d_in[5];
    const float* W_lin   = (const float*)d_in[6];
    const float* b_lin   = (const float*)d_in[7];
    float* out = (float*)d_out;

    const int N = in_sizes[0] / 128;
    const int E = in_sizes[1] / 2;
    const int NBKT = (N + 63) >> 6;            // buckets of 64 nodes (<=1600)
    const int CAP  = 1728;                     // max bucket (~1240) + pad (<=448)
    const int NBLKB = 256;
    const int CHUNK = (E + NBLKB - 1) / NBLKB; // <= 6272 (LDS dst cache)

    // workspace layout
    char* ws = (char*)d_ws;
    unsigned* h2  = (unsigned*)ws;                    // N*64 packed bf16x2
    float* a_src  = (float*)(h2 + (size_t)N * 64);    // N*4
    float* a_dst  = a_src + (size_t)N * 4;            // N*4
    unsigned* stage = (unsigned*)(a_dst + (size_t)N * 4); // NBKT*CAP (padded)
    int*   gcur   = (int*)(stage + (size_t)NBKT * CAP);   // NBKT

    k_gemm_init<<<513, 256, 0, stream>>>(
        x, Wg, att_src, att_dst, h2, a_src, a_dst, N, gcur, NBKT, CAP);
    k_partB2<<<NBLKB, 256, 0, stream>>>(ei, gcur, stage, E, NBKT, CHUNK);
    k_aggC<<<NBKT, 256, 0, stream>>>(stage, gcur, a_src, a_dst, h2,
                                     b_gat, W_lin, b_lin, out, N, CAP);
}

// Round 18
// 134.912 us; speedup vs baseline: 1.3004x; 1.0526x over previous
//
#include <hip/hip_runtime.h>

#define NSLOPE  0.2f
#define LEXP(v) __expf((v) >= 0.f ? (v) : NSLOPE * (v))

typedef __attribute__((ext_vector_type(8))) short bf16x8;
typedef __attribute__((ext_vector_type(4))) float f32x4;

__device__ __forceinline__ unsigned bf16_rne(float f) {
    unsigned x = __float_as_uint(f);
    return (x + 0x7fffu + ((x >> 16) & 1u)) >> 16;
}
__device__ __forceinline__ float bf_lo(unsigned u) { return __uint_as_float(u << 16); }
__device__ __forceinline__ float bf_hi(unsigned u) { return __uint_as_float(u & 0xffff0000u); }

// ---- Kernel 1: blocks [0,512): h2 = bf16(x@W^T) via MFMA + att dots via
// 4 extra MFMAs against watt = att@W. Block 512: init gcur[b] = b*CAP.
__global__ __launch_bounds__(256) void k_gemm_init(
    const float* __restrict__ x, const float* __restrict__ Wg,
    const float* __restrict__ att_src, const float* __restrict__ att_dst,
    unsigned* __restrict__ h2, float* __restrict__ a_src, float* __restrict__ a_dst,
    int N, int* __restrict__ gcur, int nbkt, int cap)
{
    __shared__ unsigned short Wl[128 * 136];   // bf16 W (34.8KB)
    __shared__ unsigned short wattH[8][128];   // bf16 watt (2KB)

    const int t = threadIdx.x;

    if (blockIdx.x >= 512) {                   // ---- gcur init role ----
        for (int i = t; i < nbkt; i += 256) gcur[i] = i * cap;
        return;
    }

    // ---- GEMM role ----
    for (int i = t; i < 128 * 32; i += 256) {
        int r = i >> 5, c4 = (i & 31) * 4;
        float4 w = *(const float4*)(Wg + r * 128 + c4);
        unsigned* wp = (unsigned*)((char*)Wl + r * 272 + c4 * 2);
        wp[0] = bf16_rne(w.x) | (bf16_rne(w.y) << 16);
        wp[1] = bf16_rne(w.z) | (bf16_rne(w.w) << 16);
    }
    // watt[j][f]: j<4 -> src head j; j>=4 -> dst head j-4
    for (int idx = t; idx < 1024; idx += 256) {
        int j = idx >> 7, f = idx & 127;
        const float* av = (j < 4) ? (att_src + j * 32) : (att_dst + (j - 4) * 32);
        int hh = (j & 3) * 32;
        float s = 0.f;
        #pragma unroll 8
        for (int k = 0; k < 32; ++k)
            s += av[k] * Wg[(size_t)(hh + k) * 128 + f];
        wattH[j][f] = (unsigned short)bf16_rne(s);
    }
    __syncthreads();

    const int wave = t >> 6, l = t & 63;
    const int col = l & 15, kg = l >> 4;

    union { bf16x8 v; unsigned short s[8]; } batt[4];
    #pragma unroll
    for (int s4 = 0; s4 < 4; ++s4) {
        #pragma unroll
        for (int jj = 0; jj < 8; ++jj)
            batt[s4].s[jj] = (col < 8) ? wattH[col][s4 * 32 + kg * 8 + jj]
                                       : (unsigned short)0;
    }

    const int nwaves = 512 * 4;
    const int wid = blockIdx.x * 4 + wave;

    for (int mb = wid * 16; mb < N; mb += nwaves * 16) {
        union { bf16x8 v; unsigned u[4]; } af[4];
        int row = mb + col; if (row >= N) row = N - 1;
        const float* xr = x + (size_t)row * 128 + kg * 8;
        #pragma unroll
        for (int s = 0; s < 4; ++s) {
            float4 xa = *(const float4*)(xr + s * 32);
            float4 xb = *(const float4*)(xr + s * 32 + 4);
            af[s].u[0] = bf16_rne(xa.x) | (bf16_rne(xa.y) << 16);
            af[s].u[1] = bf16_rne(xa.z) | (bf16_rne(xa.w) << 16);
            af[s].u[2] = bf16_rne(xb.x) | (bf16_rne(xb.y) << 16);
            af[s].u[3] = bf16_rne(xb.z) | (bf16_rne(xb.w) << 16);
        }

        f32x4 acc[8];
        #pragma unroll
        for (int tl = 0; tl < 8; ++tl) acc[tl] = (f32x4){0.f, 0.f, 0.f, 0.f};
        f32x4 accd = (f32x4){0.f, 0.f, 0.f, 0.f};

        #pragma unroll
        for (int s = 0; s < 4; ++s) {
            #pragma unroll
            for (int tl = 0; tl < 8; ++tl) {
                const bf16x8 bf = *(const bf16x8*)((char*)Wl
                    + (tl * 16 + col) * 272 + (s * 32 + kg * 8) * 2);
                acc[tl] = __builtin_amdgcn_mfma_f32_16x16x32_bf16(af[s].v, bf, acc[tl], 0, 0, 0);
            }
            accd = __builtin_amdgcn_mfma_f32_16x16x32_bf16(af[s].v, batt[s].v, accd, 0, 0, 0);
        }

        #pragma unroll
        for (int tl = 0; tl < 4; ++tl) {
            #pragma unroll
            for (int r = 0; r < 4; ++r) {
                int node = mb + kg * 4 + r;
                if (node < N) {
                    unsigned w = bf16_rne(acc[tl][r]) | (bf16_rne(acc[tl + 4][r]) << 16);
                    h2[(size_t)node * 64 + tl * 16 + col] = w;
                }
            }
        }
        if (col < 8) {
            float* bp = (col < 4) ? a_src : a_dst;
            const int j = col & 3;
            #pragma unroll
            for (int r = 0; r < 4; ++r) {
                int node = mb + kg * 4 + r;
                if (node < N) bp[(size_t)node * 4 + j] = accd[r];
            }
        }
    }
}

// ---- Kernel 2: fused count + reserve + scatter into padded bucket regions.
// Buckets of 64 nodes: bucket = d>>6, dlow = d&63 packed at bit 26.
__global__ __launch_bounds__(256) void k_partB2(
    const int* __restrict__ ei, int* __restrict__ gcur,
    unsigned* __restrict__ stage, int E, int nbkt, int chunk)
{
    __shared__ int dstc[6272];
    __shared__ int lcnt[1600];
    __shared__ int lbase[1600];
    const int t = threadIdx.x;
    for (int i = t; i < nbkt; i += 256) lcnt[i] = 0;
    __syncthreads();
    const int lo = blockIdx.x * chunk, hi = min(lo + chunk, E);
    for (int e = lo + t; e < hi; e += 256) {
        int d = ei[E + e];
        dstc[e - lo] = d;
        atomicAdd(&lcnt[d >> 6], 1);
    }
    __syncthreads();
    for (int i = t; i < nbkt; i += 256) {
        int c = lcnt[i];
        lbase[i] = (c > 0) ? atomicAdd(&gcur[i], c) : 0;
    }
    __syncthreads();
    for (int e = lo + t; e < hi; e += 256) {
        int s = ei[e];
        int d = dstc[e - lo];
        int pos = atomicAdd(&lbase[d >> 6], 1);
        stage[pos] = (unsigned)s | ((unsigned)(d & 63) << 26);
    }
}

// ---- Kernel 3 (fused partC + agg), 512 threads / 8 waves per block.
// Phases: count, scan, scatter edges into LDS (bf16 exps from L2-resident
// a_src gathers), pad runs to multiples of 8. Aggregation with inline
// denominator (R12): edge metadata from LDS, h2 gathers from global,
// fp32 self-exp in-register, normalize at end, fused classifier.
__global__ __launch_bounds__(512) void k_aggC(
    const unsigned* __restrict__ stage, const int* __restrict__ gcur,
    const float* __restrict__ a_src, const float* __restrict__ a_dst,
    const unsigned* __restrict__ h2, const float* __restrict__ b_gat,
    const float* __restrict__ W_lin, const float* __restrict__ b_lin,
    float* __restrict__ out, int N, int cap)
{
    __shared__ int      eS[1728];
    __shared__ unsigned eA0[1728];
    __shared__ unsigned eA1[1728];
    __shared__ int cnt[64];
    __shared__ int cur[64];
    __shared__ int rs[64];
    __shared__ int re[64];
    __shared__ float adl[64][4];

    const int b = blockIdx.x, t = threadIdx.x;
    const int wave = t >> 6, l = t & 63;

    if (t < 64) {
        cnt[t] = 0;
        int n = (b << 6) + t;
        float4 v = (n < N) ? *(const float4*)(a_dst + (size_t)n * 4)
                           : make_float4(0.f, 0.f, 0.f, 0.f);
        *(float4*)adl[t] = v;
    }
    __syncthreads();
    const int slo = b * cap;
    const int ecnt = gcur[b] - slo;
    for (int e = t; e < ecnt; e += 512)
        atomicAdd(&cnt[stage[slo + e] >> 26], 1);
    __syncthreads();
    if (t < 64) {                   // single-wave scan (wave 0)
        int v = cnt[t];
        int pv = (v + 7) & ~7;      // padded run length
        int sc = pv;
        #pragma unroll
        for (int m = 1; m < 64; m <<= 1) {
            int u = __shfl_up(sc, m);
            if (t >= m) sc += u;
        }
        int c0 = sc - pv;           // LDS-local offset
        cur[t] = c0;
        rs[t] = c0; re[t] = c0 + pv;
    }
    __syncthreads();
    for (int e = t; e < ecnt; e += 512) {
        unsigned u = stage[slo + e];
        int s  = (int)(u & 0x3FFFFFFu);
        int dl = (int)(u >> 26);
        float4 av = *(const float4*)(a_src + (size_t)s * 4);
        float x0 = LEXP(av.x + adl[dl][0]);
        float x1 = LEXP(av.y + adl[dl][1]);
        float x2 = LEXP(av.z + adl[dl][2]);
        float x3 = LEXP(av.w + adl[dl][3]);
        int pos = atomicAdd(&cur[dl], 1);
        eS[pos]  = s;
        eA0[pos] = bf16_rne(x0) | (bf16_rne(x2) << 16);
        eA1[pos] = bf16_rne(x1) | (bf16_rne(x3) << 16);
    }
    __syncthreads();
    if (t < 64) {
        int n = (b << 6) + t;
        if (n < N) {
            const int e1 = cur[t], pe = re[t];
            for (int i = e1; i < pe; ++i) {   // pad: own row, alpha 0
                eS[i] = n; eA0[i] = 0u; eA1[i] = 0u;
            }
        }
    }
    __syncthreads();

    // ---- aggregation: wave w handles local nodes w, w+8, ... ----
    const int m    = l & 31;
    const int half = l >> 5;
    const int cch  = 2 * m;
    const int hsel = m >> 4;
    const unsigned* eAh = hsel ? eA1 : eA0;

    for (int ln = wave; ln < 64; ln += 8) {
        int n = (b << 6) + ln;
        if (n >= N) break;
        const int start = rs[ln], end = re[ln];
        float a00 = 0.f, a01 = 0.f, a10 = 0.f, a11 = 0.f;
        float dA = 0.f, dB = 0.f;

        int i = start;
        for (; i + 16 <= end; i += 16) {
            int sk[8]; unsigned d[8]; uint2 u[8];
            #pragma unroll
            for (int k = 0; k < 8; ++k) {
                int j = i + 2 * k + half;
                sk[k] = eS[j];
                d[k]  = eAh[j];
            }
            #pragma unroll
            for (int k = 0; k < 8; ++k)
                u[k] = *(const uint2*)(h2 + (size_t)sk[k] * 64 + cch);
            #pragma unroll
            for (int k = 0; k < 8; ++k) {
                float wl = bf_lo(d[k]), wh = bf_hi(d[k]);
                dA += wl; dB += wh;
                a00 += wl * bf_lo(u[k].x); a01 += wh * bf_hi(u[k].x);
                a10 += wl * bf_lo(u[k].y); a11 += wh * bf_hi(u[k].y);
            }
        }
        if (i < end) {               // exactly 8 remaining (padded)
            int sk[4]; unsigned d[4]; uint2 u[4];
            #pragma unroll
            for (int k = 0; k < 4; ++k) {
                int j = i + 2 * k + half;
                sk[k] = eS[j];
                d[k]  = eAh[j];
            }
            #pragma unroll
            for (int k = 0; k < 4; ++k)
                u[k] = *(const uint2*)(h2 + (size_t)sk[k] * 64 + cch);
            #pragma unroll
            for (int k = 0; k < 4; ++k) {
                float wl = bf_lo(d[k]), wh = bf_hi(d[k]);
                dA += wl; dB += wh;
                a00 += wl * bf_lo(u[k].x); a01 += wh * bf_hi(u[k].x);
                a10 += wl * bf_lo(u[k].y); a11 += wh * bf_hi(u[k].y);
            }
        }

        a00 += __shfl_xor(a00, 32);
        a01 += __shfl_xor(a01, 32);
        a10 += __shfl_xor(a10, 32);
        a11 += __shfl_xor(a11, 32);
        dA  += __shfl_xor(dA, 32);
        dB  += __shfl_xor(dB, 32);

        // self-loop (fp32 exp, unnormalized), then normalize
        {
            float sA = LEXP(a_src[(size_t)n * 4 + hsel]     + adl[ln][hsel]);
            float sB = LEXP(a_src[(size_t)n * 4 + 2 + hsel] + adl[ln][2 + hsel]);
            uint2 u = *(const uint2*)(h2 + (size_t)n * 64 + cch);
            a00 += sA * bf_lo(u.x); a01 += sB * bf_hi(u.x);
            a10 += sA * bf_lo(u.y); a11 += sB * bf_hi(u.y);
            dA += sA; dB += sB;
        }
        const float ivA = 1.f / dA, ivB = 1.f / dB;
        a00 *= ivA; a01 *= ivB; a10 *= ivA; a11 *= ivB;

        float r0 = fmaxf(a00 + b_gat[cch],      0.f);
        float r1 = fmaxf(a01 + b_gat[cch + 64], 0.f);
        float r2 = fmaxf(a10 + b_gat[cch + 1],  0.f);
        float r3 = fmaxf(a11 + b_gat[cch + 65], 0.f);
        float p0 = r0 * W_lin[cch]       + r1 * W_lin[cch + 64]
                 + r2 * W_lin[cch + 1]   + r3 * W_lin[cch + 65];
        float p1 = r0 * W_lin[128 + cch]     + r1 * W_lin[128 + cch + 64]
                 + r2 * W_lin[128 + cch + 1] + r3 * W_lin[128 + cch + 65];
        #pragma unroll
        for (int s = 1; s < 32; s <<= 1) {
            p0 += __shfl_xor(p0, s);
            p1 += __shfl_xor(p1, s);
        }
        if (l == 0) {
            out[(size_t)n * 2]     = p0 + b_lin[0];
            out[(size_t)n * 2 + 1] = p1 + b_lin[1];
        }
    }
}

// ---------------- launch ----------------
extern "C" void kernel_launch(void* const* d_in, const int* in_sizes, int n_in,
                              void* d_out, int out_size, void* d_ws, size_t ws_size,
                              hipStream_t stream)
{
    const float* x       = (const float*)d_in[0];
    const int*   ei      = (const int*)d_in[1];
    const float* Wg      = (const float*)d_in[2];
    const float* att_src = (const float*)d_in[3];
    const float* att_dst = (const float*)d_in[4];
    const float* b_gat   = (const float*)d_in[5];
    const float* W_lin   = (const float*)d_in[6];
    const float* b_lin   = (const float*)d_in[7];
    float* out = (float*)d_out;

    const int N = in_sizes[0] / 128;
    const int E = in_sizes[1] / 2;
    const int NBKT = (N + 63) >> 6;            // buckets of 64 nodes (<=1600)
    const int CAP  = 1728;                     // max bucket (~1280) + pad (<=448)
    const int NBLKB = 256;
    const int CHUNK = (E + NBLKB - 1) / NBLKB; // <= 6272 (LDS dst cache)

    // workspace layout
    char* ws = (char*)d_ws;
    unsigned* h2  = (unsigned*)ws;                    // N*64 packed bf16x2
    float* a_src  = (float*)(h2 + (size_t)N * 64);    // N*4
    float* a_dst  = a_src + (size_t)N * 4;            // N*4
    unsigned* stage = (unsigned*)(a_dst + (size_t)N * 4); // NBKT*CAP (padded)
    int*   gcur   = (int*)(stage + (size_t)NBKT * CAP);   // NBKT

    k_gemm_init<<<513, 256, 0, stream>>>(
        x, Wg, att_src, att_dst, h2, a_src, a_dst, N, gcur, NBKT, CAP);
    k_partB2<<<NBLKB, 256, 0, stream>>>(ei, gcur, stage, E, NBKT, CHUNK);
    k_aggC<<<NBKT, 512, 0, stream>>>(stage, gcur, a_src, a_dst, h2,
                                     b_gat, W_lin, b_lin, out, N, CAP);
}